// Round 1
// baseline (929.144 us; speedup 1.0000x reference)
//
#include <hip/hip_runtime.h>

// Batched matvec: f[m] = hess[m] (DxD) @ ns[m] (D), M molecules, D = 3*N_AT.
// Memory-bound: hess is streamed exactly once (737 MB at default sizes).
// One 64-lane wave per output row; float4 loads; shfl_xor reduction.

template <int D>
__global__ __launch_bounds__(256) void forceagg_kernel(
    const float* __restrict__ ns,    // [M][D]
    const float* __restrict__ hess,  // [M*D][D]
    float* __restrict__ out,         // [M][D]
    int total_rows)
{
    constexpr int DV4 = D / 4;  // 75 for D=300; rows are 16B-aligned (D*4 % 16 == 0)
    const int lane   = threadIdx.x & 63;
    const int wave   = blockIdx.x * (blockDim.x >> 6) + (threadIdx.x >> 6);
    const int nwaves = gridDim.x * (blockDim.x >> 6);

    for (int row = wave; row < total_rows; row += nwaves) {
        const int m = row / D;  // compile-time D -> mul-hi, no divide
        const float4* __restrict__ hrow =
            reinterpret_cast<const float4*>(hess + (size_t)row * D);
        const float4* __restrict__ nvec =
            reinterpret_cast<const float4*>(ns + (size_t)m * D);

        float acc = 0.0f;
        {
            float4 h = hrow[lane];
            float4 n = nvec[lane];
            acc = h.x * n.x + h.y * n.y + h.z * n.z + h.w * n.w;
        }
        if constexpr (DV4 > 64) {
            if (lane < DV4 - 64) {
                float4 h = hrow[64 + lane];
                float4 n = nvec[64 + lane];
                acc += h.x * n.x + h.y * n.y + h.z * n.z + h.w * n.w;
            }
        }

        // 64-lane butterfly reduction
        #pragma unroll
        for (int off = 32; off > 0; off >>= 1)
            acc += __shfl_xor(acc, off, 64);

        if (lane == 0) out[row] = acc;
    }
}

// Generic fallback for unexpected D (scalar loads, runtime divide).
__global__ __launch_bounds__(256) void forceagg_generic(
    const float* __restrict__ ns,
    const float* __restrict__ hess,
    float* __restrict__ out,
    int total_rows, int D)
{
    const int lane   = threadIdx.x & 63;
    const int wave   = blockIdx.x * (blockDim.x >> 6) + (threadIdx.x >> 6);
    const int nwaves = gridDim.x * (blockDim.x >> 6);

    for (int row = wave; row < total_rows; row += nwaves) {
        const int m = row / D;
        const float* __restrict__ hrow = hess + (size_t)row * D;
        const float* __restrict__ nvec = ns + (size_t)m * D;
        float acc = 0.0f;
        for (int k = lane; k < D; k += 64)
            acc += hrow[k] * nvec[k];
        #pragma unroll
        for (int off = 32; off > 0; off >>= 1)
            acc += __shfl_xor(acc, off, 64);
        if (lane == 0) out[row] = acc;
    }
}

extern "C" void kernel_launch(void* const* d_in, const int* in_sizes, int n_in,
                              void* d_out, int out_size, void* d_ws, size_t ws_size,
                              hipStream_t stream) {
    const float* ns   = (const float*)d_in[0];  // [M*N_AT, 3] == [M, D]
    const float* hess = (const float*)d_in[1];  // [M*D, D]
    // d_in[2] (idx_m) and d_in[3] (n_atoms) are not needed: layout is uniform.
    float* out = (float*)d_out;                 // [M*N_AT, 3] == [M, D]

    const int M    = in_sizes[3];               // n_atoms has M entries
    const int n_at = in_sizes[2] / M;           // idx_m has M*N_AT entries
    const int D    = 3 * n_at;
    const int total_rows = M * D;               // == out_size

    const int block = 256;                      // 4 waves/block
    // 2048 blocks * 4 waves = 8192 waves = 32 waves/CU on 256 CUs (full occupancy)
    int grid = (total_rows + 3) / 4;            // one wave per row if small
    if (grid > 2048) grid = 2048;

    if (D == 300) {
        forceagg_kernel<300><<<grid, block, 0, stream>>>(ns, hess, out, total_rows);
    } else if (D % 4 == 0 && D / 4 <= 128 && D / 4 > 64) {
        // unexpected-but-similar uniform sizes would need their own instantiation;
        // fall through to generic for safety
        forceagg_generic<<<grid, block, 0, stream>>>(ns, hess, out, total_rows, D);
    } else {
        forceagg_generic<<<grid, block, 0, stream>>>(ns, hess, out, total_rows, D);
    }
}